// Round 14
// baseline (162.560 us; speedup 1.0000x reference)
//
#include <hip/hip_runtime.h>
#include <math.h>

#define B_  8
#define C_  64
#define H_  128
#define W_  128
#define KK_ 9
#define CO_ 64
#define HW_ (H_*W_)
#define CK_ 576

typedef _Float16 f16x8 __attribute__((ext_vector_type(8)));
typedef _Float16 h2    __attribute__((ext_vector_type(2)));
typedef __attribute__((ext_vector_type(4))) float f32x4;

__device__ inline unsigned pkrtz(float a, float b){
    auto v = __builtin_amdgcn_cvt_pkrtz(a, b);   // __fp16x2 on this toolchain
    union{decltype(v) h; unsigned u;} c; c.h = v; return c.u;
}
__device__ inline h2 u2h(unsigned u){ union{unsigned x; h2 h;} c; c.x = u; return c.h; }
__device__ inline unsigned h2u(h2 v){ union{h2 h; unsigned u;} c; c.h = v; return c.u; }
__device__ inline unsigned short f2h(float f){
    _Float16 h = (_Float16)f;
    union{_Float16 h; unsigned short s;} c; c.h = h; return c.s;
}
// broadcast lo/hi f16 of a dword into both halves (1 v_perm_b32 each)
__device__ inline h2 bcast_lo(unsigned u){ return u2h(__builtin_amdgcn_perm(u, u, 0x01000100)); }
__device__ inline h2 bcast_hi(unsigned u){ return u2h(__builtin_amdgcn_perm(u, u, 0x03020302)); }

// ---- transpose_prep: fused x NCHW->NHWC f16 transpose + weight repack ----
__global__ __launch_bounds__(256) void transpose_prep(
    const float* __restrict__ x, unsigned short* __restrict__ xt,
    const float* __restrict__ w_dcn, const float* __restrict__ w_off,
    unsigned short* __restrict__ w_bf, unsigned short* __restrict__ wA)
{
    __shared__ unsigned tb[64 * 33];          // [pix][ch-pair], stride 33
    if (blockIdx.x >= B_ * 256) {             // weight-repack tail blocks
        int i = (blockIdx.x - B_ * 256) * 256 + threadIdx.x;
        if (i < 64 * CK_) {
            int o = i / CK_, r = i % CK_;
            int tap = r >> 6, c = r & 63;
            w_bf[i] = f2h(w_dcn[o * CK_ + c * 9 + tap]);
        } else {
            int j = i - 64 * CK_;             // 0 .. 32*576-1
            int o = j / CK_, r = j % CK_;
            int tap = r >> 6, c = r & 63;
            float v = (o < 27) ? w_off[o * CK_ + c * 9 + tap] : 0.f;
            wA[j] = f2h(v);
        }
        return;
    }
    int b = blockIdx.x >> 8;
    int pixbase = (blockIdx.x & 255) * 64;
    int t = threadIdx.x;
    #pragma unroll
    for (int i = 0; i < 2; ++i) {
        int idx = i * 256 + t;                // 0..511
        int cp = idx >> 4;                    // ch-pair 0..31
        int p4 = (idx & 15) * 4;              // pix 0..60 step 4
        const float* r0 = x + ((size_t)(b * C_) + 2 * cp    ) * HW_ + pixbase + p4;
        const float* r1 = x + ((size_t)(b * C_) + 2 * cp + 1) * HW_ + pixbase + p4;
        float4 f0 = *(const float4*)r0;
        float4 f1 = *(const float4*)r1;
        tb[(p4 + 0) * 33 + cp] = pkrtz(f0.x, f1.x);
        tb[(p4 + 1) * 33 + cp] = pkrtz(f0.y, f1.y);
        tb[(p4 + 2) * 33 + cp] = pkrtz(f0.z, f1.z);
        tb[(p4 + 3) * 33 + cp] = pkrtz(f0.w, f1.w);
    }
    __syncthreads();
    unsigned* xo = (unsigned*)xt + ((size_t)b * HW_ + pixbase) * 32;
    #pragma unroll
    for (int i = 0; i < 2; ++i) {
        int idx = i * 256 + t;
        int pix = idx >> 3, j = idx & 7;
        uint4 v;
        v.x = tb[pix * 33 + j * 4 + 0];
        v.y = tb[pix * 33 + j * 4 + 1];
        v.z = tb[pix * 33 + j * 4 + 2];
        v.w = tb[pix * 33 + j * 4 + 3];
        *(uint4*)(xo + pix * 32 + j * 4) = v;   // contiguous 1KB per wave-instr
    }
}

// ==== ROUND 14: dcn18 — 32-px tiles / 128 threads: more independent blocks =
// 4th structural null (r13) + VGPR pinned 48 across 5 pipeline attempts =>
// within-block ILP unreachable; kernel is barrier-group-latency bound with
// only 4 independent groups/CU in lockstep. Lever: HALVE the tile -> 2-wave
// blocks, ~16.5KB LDS -> 9 resident blocks/CU (2.2x independent groups,
// half-size barriers, phase desync across 16 sequential blocks/CU).
// Per-lane work & gather shape (8x128B segs/instr) identical; per-accum
// MFMA k-order & blend math identical -> bit-exact.
// Pre-commit: dur>=66 = 5th null across all axes -> declare floor.

#define PXB 128                               // bytes per staged halo pixel
#define ROWB (34 * PXB)                       // 4352 B per staged row
#define SSTRB 144                             // sS row stride bytes
#define SBUF (32 * SSTRB)                     // 4608 B per tap buffer

__global__ __launch_bounds__(128, 4) void dcn18(
    const unsigned short* __restrict__ xt,    // f16 NHWC
    const unsigned short* __restrict__ wA,    // offset-conv weights [32][576] f16
    const float* __restrict__ b_off,
    const unsigned short* __restrict__ w_bf,  // dcn weights [64][576] f16
    float* __restrict__ out)
{
    __shared__ __align__(16) unsigned char uni[13056];  // halo | om | sS x2
    __shared__ uint2 scr_w[288];              // 2304 B, live through Phase B
    __shared__ int   scr_o[288];              // 1152 B
    unsigned char* xrow = uni;                // 13056 B halo (3 x 34 px)
    float* om = (float*)uni;                  // 3564 B after Phase A
    unsigned char* sS = uni;                  // 2 x 4608 B in Phase B

    int tile = blockIdx.x;                    // 4096 tiles of 32 px
    int b  = tile >> 9;
    int p0 = (tile & 511) * 32;
    int y  = p0 >> 7;
    int x0 = p0 & 127;                        // 0,32,64,96
    int t  = threadIdx.x;                     // 0..127
    int lane = t & 63, w = t >> 6;            // 2 waves
    int m = lane & 15, q = lane >> 4;

    const unsigned short* xbr = xt + (size_t)(b * HW_) * 64;

    // ---- stage halo: rows y-1..y+1, cols x0-1..x0+32 (34), zero-padded.
    // Chunk g of pixel c stored at (g^(c&7))*16 within the pixel's 128B. ----
    for (int i = t; i < 3 * 34 * 8; i += 128) {
        int r = i / 272;
        int rem = i - r * 272;
        int c = rem >> 3;                     // 0..33
        int g = rem & 7;
        int yy = y - 1 + r;
        int xx = x0 - 1 + c;
        uint4 v = {0, 0, 0, 0};
        if (yy >= 0 && yy < H_ && xx >= 0 && xx < W_)
            v = *(const uint4*)(xbr + ((size_t)yy * W_ + xx) * 64 + g * 8);
        *(uint4*)(xrow + r * ROWB + c * PXB + ((g ^ (c & 7)) << 4)) = v;
    }
    __syncthreads();

    // ---- Phase A: offset conv; wave w -> outs w*16..+15, all 32 px ---------
    {
        int o0c = w * 16;

        f32x4 accc[2] = {};
        #pragma unroll
        for (int ky = 0; ky < 3; ++ky) {
            #pragma unroll
            for (int kx = 0; kx < 3; ++kx) {
                int s2 = (ky * 3 + kx) * 2;
                f16x8 A0 = *(const f16x8*)(wA + (o0c + m) * CK_ + s2 * 32 + q * 8);
                f16x8 A1 = *(const f16x8*)(wA + (o0c + m) * CK_ + (s2 + 1) * 32 + q * 8);
                #pragma unroll
                for (int nt = 0; nt < 2; ++nt) {
                    int c = nt * 16 + m + kx;           // staged col 0..33
                    const unsigned char* p = xrow + ky * ROWB + c * PXB;
                    int off0 = (q ^ (c & 7)) << 4;
                    f16x8 b0 = *(const f16x8*)(p + off0);
                    f16x8 b1 = *(const f16x8*)(p + (off0 ^ 64));
                    accc[nt] = __builtin_amdgcn_mfma_f32_16x16x32_f16(A0, b0, accc[nt], 0, 0, 0);
                    accc[nt] = __builtin_amdgcn_mfma_f32_16x16x32_f16(A1, b1, accc[nt], 0, 0, 0);
                }
            }
        }
        __syncthreads();      // halo dead; om about to overwrite the region
        #pragma unroll
        for (int nt = 0; nt < 2; ++nt) {
            #pragma unroll
            for (int r = 0; r < 4; ++r) {
                int j = o0c + q * 4 + r;
                if (j < 27)
                    om[j * 33 + nt * 16 + m] = accc[nt][r] + b_off[j];
            }
        }
    }
    __syncthreads();

    // ---- Phase 0: 288 pixel-taps -> 4xf16 weights + packed offsets ---------
    for (int i = t; i < 288; i += 128) {
        int k = i >> 5, sp = i & 31;
        float dy = om[(2 * k)     * 33 + sp];
        float dx = om[(2 * k + 1) * 33 + sp];
        float mk = 1.f / (1.f + __expf(-om[(18 + k) * 33 + sp]));
        float py = dy + (float)(y - 1 + k / 3);
        float px = dx + (float)(x0 + sp - 1 + k % 3);
        float fy = floorf(py), fx = floorf(px);
        int iy = (int)fy, ix = (int)fx;
        float ay = py - fy, ax = px - fx;
        float wy0 = (iy >= 0  && iy < H_)     ? (1.f - ay) : 0.f;
        float wy1 = (iy >= -1 && iy < H_ - 1) ? ay         : 0.f;
        float wx0 = (ix >= 0  && ix < W_)     ? (1.f - ax) : 0.f;
        float wx1 = (ix >= -1 && ix < W_ - 1) ? ax         : 0.f;
        int iy0 = min(max(iy, 0), H_ - 1);
        int iy1 = min(max(iy + 1, 0), H_ - 1);
        int ix0 = min(max(ix, 0), W_ - 1);
        int ix1 = min(max(ix + 1, 0), W_ - 1);
        float w00 = wy0*wx0*mk, w01 = wy0*wx1*mk, w10 = wy1*wx0*mk, w11 = wy1*wx1*mk;
        uint2 wv;
        wv.x = pkrtz(w00, w01);               // lo=w00 hi=w01
        wv.y = pkrtz(w10, w11);               // lo=w10 hi=w11
        scr_w[i] = wv;
        int off00 = (iy0 * W_ + ix0) * 128;   // bytes (64ch * 2B f16)
        scr_o[i] = off00 | ((ix1 != ix0) << 22) | ((iy1 != iy0) << 23);
    }

    int o0 = w * 32;                          // wave's 32 out-channels
    __syncthreads();        // scr ready; om region (sS) now free

    // ---- Phase B: tap double-buffered produce + GEMM, 1 barrier per tap ----
    int cq = lane & 7;
    int g  = lane >> 3;
    const unsigned char* xb = (const unsigned char*)xbr;
    f32x4 acc[4] = {};                        // [jo*2+nt]
    int piB = w * 8 + g;                      // 0..15; P = piB + k*16

#define PROD(K) do {                                                        \
        const int k_ = (K);                                                 \
        uint2 wC_ = {}; int pC_ = 0;                                        \
        if (k_ + 2 < 18) {                                                  \
            int P = piB + (k_ + 2) * 16;                                    \
            wC_ = scr_w[P]; pC_ = scr_o[P];                                 \
        }                                                                   \
        uint4 n00 = {}, n01 = {}, n10 = {}, n11 = {};                       \
        if (k_ + 1 < 18) {                                                  \
            const unsigned char* a0 = xb + (pB_ & 0x3FFFFF) + cq * 16;      \
            int dxb = (pB_ >> 15) & 128;                                    \
            int dyb = (pB_ >> 9)  & 16384;                                  \
            n00 = *(const uint4*)(a0);                                      \
            n01 = *(const uint4*)(a0 + dxb);                                \
            n10 = *(const uint4*)(a0 + dyb);                                \
            n11 = *(const uint4*)(a0 + dyb + dxb);                          \
        }                                                                   \
        h2 w00 = bcast_lo(wA_.x), w01 = bcast_hi(wA_.x);                    \
        h2 w10 = bcast_lo(wA_.y), w11 = bcast_hi(wA_.y);                    \
        uint4 o4; h2 r;                                                     \
        r = w00*u2h(a00.x) + w01*u2h(a01.x) + w10*u2h(a10.x) + w11*u2h(a11.x); o4.x = h2u(r); \
        r = w00*u2h(a00.y) + w01*u2h(a01.y) + w10*u2h(a10.y) + w11*u2h(a11.y); o4.y = h2u(r); \
        r = w00*u2h(a00.z) + w01*u2h(a01.z) + w10*u2h(a10.z) + w11*u2h(a11.z); o4.z = h2u(r); \
        r = w00*u2h(a00.w) + w01*u2h(a01.w) + w10*u2h(a10.w) + w11*u2h(a11.w); o4.w = h2u(r); \
        int sp_ = piB + (k_ & 1) * 16;                                      \
        *(uint4*)&sS[((k_ >> 1) & 1) * SBUF + sp_ * SSTRB + cq * 16] = o4;  \
        wA_ = wB_; wB_ = wC_; pB_ = pC_;                                    \
        a00 = n00; a01 = n01; a10 = n10; a11 = n11;                         \
    } while (0)

    uint2 wA_, wB_; int pB_;
    uint4 a00, a01, a10, a11;
    {
        wA_ = scr_w[piB];      int oo = scr_o[piB];
        wB_ = scr_w[piB + 16]; pB_ = scr_o[piB + 16];
        const unsigned char* a0 = xb + (oo & 0x3FFFFF) + cq * 16;
        int dxb = (oo >> 15) & 128;
        int dyb = (oo >> 9)  & 16384;
        a00 = *(const uint4*)(a0);
        a01 = *(const uint4*)(a0 + dxb);
        a10 = *(const uint4*)(a0 + dyb);
        a11 = *(const uint4*)(a0 + dyb + dxb);
    }

    // A-frag double-buffer: [jo][ks] for current tap
    f16x8 AfC00 = *(const f16x8*)(w_bf + (o0 +      m) * CK_ + 0 * 32 + q * 8);
    f16x8 AfC01 = *(const f16x8*)(w_bf + (o0 +      m) * CK_ + 1 * 32 + q * 8);
    f16x8 AfC10 = *(const f16x8*)(w_bf + (o0 + 16 + m) * CK_ + 0 * 32 + q * 8);
    f16x8 AfC11 = *(const f16x8*)(w_bf + (o0 + 16 + m) * CK_ + 1 * 32 + q * 8);

    PROD(0); PROD(1);
    __syncthreads();

    #pragma unroll
    for (int tp = 0; tp < 9; ++tp) {
        f16x8 AfN00, AfN01, AfN10, AfN11;
        if (tp < 8) {
            PROD(2 * tp + 2);
            PROD(2 * tp + 3);
            AfN00 = *(const f16x8*)(w_bf + (o0 +      m) * CK_ + (2 * tp + 2) * 32 + q * 8);
            AfN01 = *(const f16x8*)(w_bf + (o0 +      m) * CK_ + (2 * tp + 3) * 32 + q * 8);
            AfN10 = *(const f16x8*)(w_bf + (o0 + 16 + m) * CK_ + (2 * tp + 2) * 32 + q * 8);
            AfN11 = *(const f16x8*)(w_bf + (o0 + 16 + m) * CK_ + (2 * tp + 3) * 32 + q * 8);
        }
        const unsigned char* sb = sS + (tp & 1) * SBUF;
        // ks = 0 (k-slice 2tp): B rows nt*16+m, ch 0..31
        #pragma unroll
        for (int nt = 0; nt < 2; ++nt) {
            f16x8 bb = *(const f16x8*)&sb[(nt * 16 + m) * SSTRB + q * 16];
            acc[0 * 2 + nt] = __builtin_amdgcn_mfma_f32_16x16x32_f16(AfC00, bb, acc[0 * 2 + nt], 0, 0, 0);
            acc[1 * 2 + nt] = __builtin_amdgcn_mfma_f32_16x16x32_f16(AfC10, bb, acc[1 * 2 + nt], 0, 0, 0);
        }
        // ks = 1 (k-slice 2tp+1): ch 32..63
        #pragma unroll
        for (int nt = 0; nt < 2; ++nt) {
            f16x8 bb = *(const f16x8*)&sb[(nt * 16 + m) * SSTRB + 64 + q * 16];
            acc[0 * 2 + nt] = __builtin_amdgcn_mfma_f32_16x16x32_f16(AfC01, bb, acc[0 * 2 + nt], 0, 0, 0);
            acc[1 * 2 + nt] = __builtin_amdgcn_mfma_f32_16x16x32_f16(AfC11, bb, acc[1 * 2 + nt], 0, 0, 0);
        }
        if (tp < 8) {
            __syncthreads();      // buf (tp+1)&1 ready; buf tp&1 free
            AfC00 = AfN00; AfC01 = AfN01; AfC10 = AfN10; AfC11 = AfN11;
        }
    }
#undef PROD

    // Epilogue: col(px)=m, row(o)=q*4+reg
    #pragma unroll
    for (int jo = 0; jo < 2; ++jo) {
        #pragma unroll
        for (int nt = 0; nt < 2; ++nt) {
            #pragma unroll
            for (int r = 0; r < 4; ++r) {
                int o = o0 + jo * 16 + q * 4 + r;
                out[((size_t)(b * CO_ + o)) * HW_ + p0 + nt * 16 + m] = acc[jo * 2 + nt][r];
            }
        }
    }
}

extern "C" void kernel_launch(void* const* d_in, const int* in_sizes, int n_in,
                              void* d_out, int out_size, void* d_ws, size_t ws_size,
                              hipStream_t stream)
{
    const float* x     = (const float*)d_in[0];
    const float* w_off = (const float*)d_in[1];
    const float* b_off = (const float*)d_in[2];
    const float* w_dcn = (const float*)d_in[3];
    float* out = (float*)d_out;

    unsigned short* xt   = (unsigned short*)d_ws;                // 16.8 MB
    unsigned short* w_bf = xt + (size_t)B_ * HW_ * 64;           // 73.7 KB
    unsigned short* wA   = w_bf + 64 * CK_;                      // 36.9 KB

    transpose_prep<<<B_ * 256 + 216, 256, 0, stream>>>(x, xt, w_dcn, w_off, w_bf, wA);
    dcn18<<<B_ * 512, 128, 0, stream>>>(xt, wA, b_off, w_bf, out);
}

// Round 15
// 146.171 us; speedup vs baseline: 1.1121x; 1.1121x over previous
//
#include <hip/hip_runtime.h>
#include <math.h>

#define B_  8
#define C_  64
#define H_  128
#define W_  128
#define KK_ 9
#define CO_ 64
#define HW_ (H_*W_)
#define CK_ 576

typedef _Float16 f16x8 __attribute__((ext_vector_type(8)));
typedef _Float16 h2    __attribute__((ext_vector_type(2)));
typedef __attribute__((ext_vector_type(4))) float f32x4;

__device__ inline unsigned pkrtz(float a, float b){
    auto v = __builtin_amdgcn_cvt_pkrtz(a, b);   // __fp16x2 on this toolchain
    union{decltype(v) h; unsigned u;} c; c.h = v; return c.u;
}
__device__ inline h2 u2h(unsigned u){ union{unsigned x; h2 h;} c; c.x = u; return c.h; }
__device__ inline unsigned h2u(h2 v){ union{h2 h; unsigned u;} c; c.h = v; return c.u; }
__device__ inline unsigned short f2h(float f){
    _Float16 h = (_Float16)f;
    union{_Float16 h; unsigned short s;} c; c.h = h; return c.s;
}
// broadcast lo/hi f16 of a dword into both halves (1 v_perm_b32 each)
__device__ inline h2 bcast_lo(unsigned u){ return u2h(__builtin_amdgcn_perm(u, u, 0x01000100)); }
__device__ inline h2 bcast_hi(unsigned u){ return u2h(__builtin_amdgcn_perm(u, u, 0x03020302)); }

// ---- transpose_prep: fused x NCHW->NHWC f16 transpose + weight repack ----
__global__ __launch_bounds__(256) void transpose_prep(
    const float* __restrict__ x, unsigned short* __restrict__ xt,
    const float* __restrict__ w_dcn, const float* __restrict__ w_off,
    unsigned short* __restrict__ w_bf, unsigned short* __restrict__ wA)
{
    __shared__ unsigned tb[64 * 33];          // [pix][ch-pair], stride 33
    if (blockIdx.x >= B_ * 256) {             // weight-repack tail blocks
        int i = (blockIdx.x - B_ * 256) * 256 + threadIdx.x;
        if (i < 64 * CK_) {
            int o = i / CK_, r = i % CK_;
            int tap = r >> 6, c = r & 63;
            w_bf[i] = f2h(w_dcn[o * CK_ + c * 9 + tap]);
        } else {
            int j = i - 64 * CK_;             // 0 .. 32*576-1
            int o = j / CK_, r = j % CK_;
            int tap = r >> 6, c = r & 63;
            float v = (o < 27) ? w_off[o * CK_ + c * 9 + tap] : 0.f;
            wA[j] = f2h(v);
        }
        return;
    }
    int b = blockIdx.x >> 8;
    int pixbase = (blockIdx.x & 255) * 64;
    int t = threadIdx.x;
    #pragma unroll
    for (int i = 0; i < 2; ++i) {
        int idx = i * 256 + t;                // 0..511
        int cp = idx >> 4;                    // ch-pair 0..31
        int p4 = (idx & 15) * 4;              // pix 0..60 step 4
        const float* r0 = x + ((size_t)(b * C_) + 2 * cp    ) * HW_ + pixbase + p4;
        const float* r1 = x + ((size_t)(b * C_) + 2 * cp + 1) * HW_ + pixbase + p4;
        float4 f0 = *(const float4*)r0;
        float4 f1 = *(const float4*)r1;
        tb[(p4 + 0) * 33 + cp] = pkrtz(f0.x, f1.x);
        tb[(p4 + 1) * 33 + cp] = pkrtz(f0.y, f1.y);
        tb[(p4 + 2) * 33 + cp] = pkrtz(f0.z, f1.z);
        tb[(p4 + 3) * 33 + cp] = pkrtz(f0.w, f1.w);
    }
    __syncthreads();
    unsigned* xo = (unsigned*)xt + ((size_t)b * HW_ + pixbase) * 32;
    #pragma unroll
    for (int i = 0; i < 2; ++i) {
        int idx = i * 256 + t;
        int pix = idx >> 3, j = idx & 7;
        uint4 v;
        v.x = tb[pix * 33 + j * 4 + 0];
        v.y = tb[pix * 33 + j * 4 + 1];
        v.z = tb[pix * 33 + j * 4 + 2];
        v.w = tb[pix * 33 + j * 4 + 3];
        *(uint4*)(xo + pix * 32 + j * 4) = v;   // contiguous 1KB per wave-instr
    }
}

// ==== ROUND 15: RESTORE dcn15 (round-11 verified best: dcn 67.4us, total
// 145.9us). r14's small-tile experiment regressed (84us: halo redundancy +
// per-block overhead amortized over half the work). Session ledger:
//   wins: halo staging (P1 55.6->22), fusion (-3.5), uint4 gathers (r1).
//   nulls/regressions: occupancy x3, bank-conflict swizzle, XCD swizzle,
//   asm depth-1 pipeline, tap-overlap dbuf, 32-px tiles.
// Remaining gap = barrier-group serialization the HIP compiler won't let us
// pipeline (VGPR pinned 44-56 across 5 attempts). This is the structural
// floor of this decomposition at HIP source level; restoring best-known.
#define PXB 144                               // bytes per staged halo pixel
#define ROWB (66 * PXB)                       // 9504 B per staged row
#define SSTR4 400                             // sS row stride bytes

__global__ __launch_bounds__(256, 4) void dcn15(
    const unsigned short* __restrict__ xt,    // f16 NHWC
    const unsigned short* __restrict__ wA,    // offset-conv weights [32][576] f16
    const float* __restrict__ b_off,
    const unsigned short* __restrict__ w_bf,  // dcn weights [64][576] f16
    float* __restrict__ out)
{
    __shared__ __align__(16) unsigned char xrow[3 * ROWB];  // 28512 B
    __shared__ uint2 scr_w[576];              // 4608 B, live through Phase B
    __shared__ int   scr_o[576];              // 2304 B
    float* om = (float*)xrow;                 // alias after Phase A (barrier)
    unsigned char* sS = xrow;                 // alias in Phase B (25600<=28512)

    int tile = blockIdx.x;
    int b  = tile >> 8;
    int p0 = (tile & 255) * 64;
    int y  = p0 >> 7;
    int x0 = p0 & 127;
    int t  = threadIdx.x;
    int lane = t & 63, w = t >> 6;
    int m = lane & 15, q = lane >> 4;

    const unsigned short* xbr = xt + (size_t)(b * HW_) * 64;

    // ---- stage halo: rows y-1..y+1, cols x0-1..x0+64, zeros out of range ---
    for (int i = t; i < 3 * 66 * 8; i += 256) {
        int r = i / 528;                      // 0..2
        int rem = i - r * 528;
        int c = rem >> 3;                     // 0..65
        int g = rem & 7;                      // 16B chunk within pixel
        int yy = y - 1 + r;
        int xx = x0 - 1 + c;
        uint4 v = {0, 0, 0, 0};
        if (yy >= 0 && yy < H_ && xx >= 0 && xx < W_)
            v = *(const uint4*)(xbr + ((size_t)yy * W_ + xx) * 64 + g * 8);
        *(uint4*)(xrow + r * ROWB + c * PXB + g * 16) = v;
    }
    __syncthreads();

    // ---- Phase A: offset conv; B-operand from LDS halo ---------------------
    {
        int o0c = (w & 1) * 16;
        int pxh = (w >> 1) * 32;

        f32x4 accc[2] = {};
        #pragma unroll
        for (int ky = 0; ky < 3; ++ky) {
            #pragma unroll
            for (int kx = 0; kx < 3; ++kx) {
                int s2 = (ky * 3 + kx) * 2;
                f16x8 A0 = *(const f16x8*)(wA + (o0c + m) * CK_ + s2 * 32 + q * 8);
                f16x8 A1 = *(const f16x8*)(wA + (o0c + m) * CK_ + (s2 + 1) * 32 + q * 8);
                #pragma unroll
                for (int nt = 0; nt < 2; ++nt) {
                    int c = pxh + nt * 16 + m + kx;   // staged col (0..65)
                    const unsigned char* p = xrow + ky * ROWB + c * PXB + q * 16;
                    f16x8 b0 = *(const f16x8*)p;
                    f16x8 b1 = *(const f16x8*)(p + 64);
                    accc[nt] = __builtin_amdgcn_mfma_f32_16x16x32_f16(A0, b0, accc[nt], 0, 0, 0);
                    accc[nt] = __builtin_amdgcn_mfma_f32_16x16x32_f16(A1, b1, accc[nt], 0, 0, 0);
                }
            }
        }
        __syncthreads();      // halo dead; om about to overwrite the region
        #pragma unroll
        for (int nt = 0; nt < 2; ++nt) {
            #pragma unroll
            for (int r = 0; r < 4; ++r) {
                int j = o0c + q * 4 + r;
                if (j < 27)
                    om[j * 65 + pxh + nt * 16 + m] = accc[nt][r] + b_off[j];
            }
        }
    }
    __syncthreads();

    // ---- Phase 0: offsets -> 4xf16 weights + packed offsets (LDS scr) ------
    for (int i = t; i < 576; i += 256) {
        int k = i >> 6, sp = i & 63;
        float dy = om[(2 * k)     * 65 + sp];
        float dx = om[(2 * k + 1) * 65 + sp];
        float mk = 1.f / (1.f + __expf(-om[(18 + k) * 65 + sp]));
        float py = dy + (float)(y - 1 + k / 3);
        float px = dx + (float)(x0 + sp - 1 + k % 3);
        float fy = floorf(py), fx = floorf(px);
        int iy = (int)fy, ix = (int)fx;
        float ay = py - fy, ax = px - fx;
        float wy0 = (iy >= 0  && iy < H_)     ? (1.f - ay) : 0.f;
        float wy1 = (iy >= -1 && iy < H_ - 1) ? ay         : 0.f;
        float wx0 = (ix >= 0  && ix < W_)     ? (1.f - ax) : 0.f;
        float wx1 = (ix >= -1 && ix < W_ - 1) ? ax         : 0.f;
        int iy0 = min(max(iy, 0), H_ - 1);
        int iy1 = min(max(iy + 1, 0), H_ - 1);
        int ix0 = min(max(ix, 0), W_ - 1);
        int ix1 = min(max(ix + 1, 0), W_ - 1);
        float w00 = wy0*wx0*mk, w01 = wy0*wx1*mk, w10 = wy1*wx0*mk, w11 = wy1*wx1*mk;
        uint2 wv;
        wv.x = pkrtz(w00, w01);               // lo=w00 hi=w01
        wv.y = pkrtz(w10, w11);               // lo=w10 hi=w11
        scr_w[i] = wv;
        int off00 = (iy0 * W_ + ix0) * 128;   // bytes (64ch * 2B f16)
        scr_o[i] = off00 | ((ix1 != ix0) << 22) | ((iy1 != iy0) << 23);
    }

    int o0 = w * 16;
    __syncthreads();        // scr ready; om region (sS) now free

    // ---- Phase B: verbatim dcn12 rolling pipeline --------------------------
    int cq = lane & 7;
    int g  = lane >> 3;
    const unsigned char* xb = (const unsigned char*)xbr;
    f32x4 acc[4] = {};
    int piB = w * 8 + g;

    uint2 wA_, wB_; int pB_;
    uint4 a00, a01, a10, a11;
    {
        wA_ = scr_w[piB];      int oo = scr_o[piB];
        wB_ = scr_w[piB + 32]; pB_ = scr_o[piB + 32];
        const unsigned char* a0 = xb + (oo & 0x3FFFFF) + cq * 16;
        int dxb = (oo >> 15) & 128;
        int dyb = (oo >> 9)  & 16384;
        a00 = *(const uint4*)(a0);
        a01 = *(const uint4*)(a0 + dxb);
        a10 = *(const uint4*)(a0 + dyb);
        a11 = *(const uint4*)(a0 + dyb + dxb);
    }

    #pragma unroll
    for (int chunk = 0; chunk < 3; ++chunk) {
        #pragma unroll
        for (int it6 = 0; it6 < 6; ++it6) {
            const int k = chunk * 6 + it6;
            uint2 wC_ = {}; int pC_ = 0;
            if (k + 2 < 18) {
                int P = piB + (k + 2) * 32;
                wC_ = scr_w[P]; pC_ = scr_o[P];
            }
            uint4 n00 = {}, n01 = {}, n10 = {}, n11 = {};
            if (k + 1 < 18) {
                const unsigned char* a0 = xb + (pB_ & 0x3FFFFF) + cq * 16;
                int dxb = (pB_ >> 15) & 128;
                int dyb = (pB_ >> 9)  & 16384;
                n00 = *(const uint4*)(a0);
                n01 = *(const uint4*)(a0 + dxb);
                n10 = *(const uint4*)(a0 + dyb);
                n11 = *(const uint4*)(a0 + dyb + dxb);
            }
            h2 w00 = bcast_lo(wA_.x), w01 = bcast_hi(wA_.x);
            h2 w10 = bcast_lo(wA_.y), w11 = bcast_hi(wA_.y);
            uint4 o4; h2 r;
            r = w00*u2h(a00.x) + w01*u2h(a01.x) + w10*u2h(a10.x) + w11*u2h(a11.x); o4.x = h2u(r);
            r = w00*u2h(a00.y) + w01*u2h(a01.y) + w10*u2h(a10.y) + w11*u2h(a11.y); o4.y = h2u(r);
            r = w00*u2h(a00.z) + w01*u2h(a01.z) + w10*u2h(a10.z) + w11*u2h(a11.z); o4.z = h2u(r);
            r = w00*u2h(a00.w) + w01*u2h(a01.w) + w10*u2h(a10.w) + w11*u2h(a11.w); o4.w = h2u(r);
            int sp  = (piB + (k & 1) * 32) & 63;
            int ktl = it6 >> 1;
            *(uint4*)&sS[sp * SSTR4 + ktl * 128 + cq * 16] = o4;
            wA_ = wB_; wB_ = wC_; pB_ = pC_;
            a00 = n00; a01 = n01; a10 = n10; a11 = n11;
        }
        f16x8 Af[6];
        #pragma unroll
        for (int s = 0; s < 6; ++s)
            Af[s] = *(const f16x8*)(w_bf + (o0 + m) * CK_ + (chunk * 6 + s) * 32 + q * 8);
        __syncthreads();

        #pragma unroll
        for (int s = 0; s < 6; ++s) {
            #pragma unroll
            for (int nt = 0; nt < 4; ++nt) {
                f16x8 bb = *(const f16x8*)&sS[(nt * 16 + m) * SSTR4 + s * 64 + q * 16];
                acc[nt] = __builtin_amdgcn_mfma_f32_16x16x32_f16(Af[s], bb, acc[nt], 0, 0, 0);
            }
        }
        __syncthreads();
    }

    #pragma unroll
    for (int nt = 0; nt < 4; ++nt) {
        #pragma unroll
        for (int r = 0; r < 4; ++r) {
            int o = o0 + q * 4 + r;
            out[((size_t)(b * CO_ + o)) * HW_ + p0 + nt * 16 + m] = acc[nt][r];
        }
    }
}

extern "C" void kernel_launch(void* const* d_in, const int* in_sizes, int n_in,
                              void* d_out, int out_size, void* d_ws, size_t ws_size,
                              hipStream_t stream)
{
    const float* x     = (const float*)d_in[0];
    const float* w_off = (const float*)d_in[1];
    const float* b_off = (const float*)d_in[2];
    const float* w_dcn = (const float*)d_in[3];
    float* out = (float*)d_out;

    unsigned short* xt   = (unsigned short*)d_ws;                // 16.8 MB
    unsigned short* w_bf = xt + (size_t)B_ * HW_ * 64;           // 73.7 KB
    unsigned short* wA   = w_bf + 64 * CK_;                      // 36.9 KB

    transpose_prep<<<B_ * 256 + 216, 256, 0, stream>>>(x, xt, w_dcn, w_off, w_bf, wA);
    dcn15<<<B_ * 256, 256, 0, stream>>>(xt, wA, b_off, w_bf, out);
}